// Round 1
// 755.030 us; speedup vs baseline: 1.8561x; 1.8561x over previous
//
#include <hip/hip_runtime.h>
#include <hip/hip_bf16.h>

typedef __hip_bfloat16 bf16;
#define DEVI __device__ __forceinline__

typedef __bf16 bf16x8 __attribute__((ext_vector_type(8)));
typedef __bf16 bf16x4 __attribute__((ext_vector_type(4)));
typedef float  f32x4  __attribute__((ext_vector_type(4)));

DEVI float bf2f(bf16 v) { return __bfloat162float(v); }
DEVI bf16 f2bf(float v) { return __float2bfloat16(v); }

DEVI unsigned short bfbits(float x) {
    bf16 h = __float2bfloat16(x);
    return *reinterpret_cast<unsigned short*>(&h);
}
DEVI unsigned int pack2(float x, float y) {
    return (unsigned int)bfbits(x) | ((unsigned int)bfbits(y) << 16);
}
DEVI float2 unpack2(unsigned int u) {
    float2 r;
    r.x = __uint_as_float(u << 16);
    r.y = __uint_as_float(u & 0xffff0000u);
    return r;
}
DEVI bf16x8 pack8(float4 lo, float4 hi) {
    union { unsigned int u[4]; bf16x8 v; } z;
    z.u[0] = pack2(lo.x, lo.y); z.u[1] = pack2(lo.z, lo.w);
    z.u[2] = pack2(hi.x, hi.y); z.u[3] = pack2(hi.z, hi.w);
    return z.v;
}
// LDS bf16x8 load from an 8-byte-aligned (not 16) address: two b64 halves
DEVI bf16x8 ld8h(const bf16* p) {
    bf16x4 lo = *(const bf16x4*)p;
    bf16x4 hi = *(const bf16x4*)(p + 4);
    return __builtin_shufflevector(lo, hi, 0, 1, 2, 3, 4, 5, 6, 7);
}

// ---------------------------------------------------------------------------
// Prep A: reorder qkv weights per head into [h][96][192] bf16, fold 1/sqrt(32)
// into the q rows and q bias. qkv_bb fp32 [576] in [h][96] order.
// ---------------------------------------------------------------------------
__global__ __launch_bounds__(256) void prep_attn_w(
    const float* __restrict__ qkv_w, const float* __restrict__ qkv_b,
    bf16* __restrict__ qkv_wb, float* __restrict__ qkv_bb)
{
    const float scale = 0.17677669529663687f;
    int idx = blockIdx.x * 256 + threadIdx.x;
    if (idx < 110592) {
        int c = idx % 192, d = idx / 192;
        int h = d / 96, q2 = d - h * 96, seg = q2 >> 5, rr = q2 & 31;
        float v = qkv_w[(size_t)(seg * 192 + h * 32 + rr) * 192 + c];
        if (seg == 0) v *= scale;
        qkv_wb[idx] = f2bf(v);
    }
    if (idx < 576) {
        int h = idx / 96, q2 = idx - h * 96, seg = q2 >> 5, rr = q2 & 31;
        float b = qkv_b[seg * 192 + h * 32 + rr];
        if (seg == 0) b *= scale;
        qkv_bb[idx] = b;
    }
}

// ---------------------------------------------------------------------------
// Prep B: materialize earth bias tiles biasT[wb][h][n][m] bf16 (64*6*144*144)
// ---------------------------------------------------------------------------
__global__ __launch_bounds__(256) void prep_bias(
    const float* __restrict__ bias_table, bf16* __restrict__ biasT)
{
    int idx = blockIdx.x * 256 + threadIdx.x;
    if (idx >= 7962624) return;
    int m = idx % 144;
    int n = (idx / 144) % 144;
    int r2 = idx / 20736;
    int h = r2 % 6, wb = r2 / 6;
    int tzn = n / 72, thn = (n / 12) % 6, twn = n % 12;
    int tzm = m / 72, thm = (m / 12) % 6, twm = m % 12;
    int bidx = (tzn + 2 * tzm) * 828 + (thn + 6 * thm) * 23 + (twn - twm + 11);
    biasT[idx] = f2bf(bias_table[(size_t)(bidx * 64 + wb) * 6 + h]);
}

// ---------------------------------------------------------------------------
// Kernel 1 (MFMA): windowed attention, one block per (window, head), 4 waves.
// M-tiles (9) split {0,4,8},{1,5},{2,6},{3,7} across waves.
// ---------------------------------------------------------------------------
__global__ __launch_bounds__(256, 2) void attn_mfma_kernel(
    const float* __restrict__ x, const bf16* __restrict__ qkv_wb,
    const float* __restrict__ qkv_bb, const bf16* __restrict__ biasT,
    bf16* __restrict__ attn_out)
{
    // LDS: Q [144][36] @0 (10368) | K [144][36] @10368 | VT [32][168] @20736
    //      P [144][168] @31488 (48384)  -> total 79872 B, 2 blocks/CU
    __shared__ alignas(16) char sm[79872];
    bf16* Qs  = (bf16*)sm;
    bf16* Ks  = (bf16*)(sm + 10368);
    bf16* VTs = (bf16*)(sm + 20736);
    bf16* Ps  = (bf16*)(sm + 31488);

    const int tid  = threadIdx.x;
    const int wave = tid >> 6;
    const int lane = tid & 63;
    const int quad = lane >> 4;
    const int l15  = lane & 15;
    const int wi   = blockIdx.x;
    const int head = blockIdx.y;
    const int ww_  = wi % 15;
    const int hw   = (wi / 15) % 16;
    const int zw   = wi / 240;
    const int wb   = zw * 16 + hw;

    // zero VT pad cols [144,168)
    for (int i = tid; i < 32 * 24; i += 256) {
        int d = i / 24, c = i - d * 24;
        VTs[d * 168 + 144 + c] = f2bf(0.f);
    }

    // ---- load A-fragments of x window straight from global (fp32 -> bf16) ----
    bf16x8 af[3][6];
#pragma unroll
    for (int i = 0; i < 3; ++i) {
        int mt = wave + 4 * i;
        if (mt < 9) {
            int t  = mt * 16 + l15;
            int tz = t / 72, rr = t - tz * 72;
            int th = rr / 12, tw = rr - th * 12;
            int lat = hw * 6 + th - 2;
            bool valid = (lat >= 0 && lat < 91);
            size_t base = ((size_t)((zw * 2 + tz) * 91 + (valid ? lat : 0)) * 180
                           + ww_ * 12 + tw) * 192;
#pragma unroll
            for (int ks = 0; ks < 6; ++ks) {
                float4 lo = make_float4(0.f, 0.f, 0.f, 0.f);
                float4 hi = make_float4(0.f, 0.f, 0.f, 0.f);
                if (valid) {
                    lo = *(const float4*)(x + base + ks * 32 + quad * 8);
                    hi = *(const float4*)(x + base + ks * 32 + quad * 8 + 4);
                }
                af[i][ks] = pack8(lo, hi);
            }
        }
    }

    // ---- QKV GEMM: 6 N-tiles (q0 q1 k0 k1 v0 v1) ----
    for (int nt = 0; nt < 6; ++nt) {
        const bf16* wrow = qkv_wb + (size_t)(head * 96 + nt * 16 + l15) * 192;
        bf16x8 bw[6];
#pragma unroll
        for (int ks = 0; ks < 6; ++ks)
            bw[ks] = *(const bf16x8*)(wrow + ks * 32 + quad * 8);
        float bias = qkv_bb[head * 96 + nt * 16 + l15];

        f32x4 acc[3];
#pragma unroll
        for (int i = 0; i < 3; ++i) acc[i] = (f32x4){0.f, 0.f, 0.f, 0.f};
#pragma unroll
        for (int ks = 0; ks < 6; ++ks)
#pragma unroll
            for (int i = 0; i < 3; ++i) {
                int mt = wave + 4 * i;
                if (mt < 9)
                    acc[i] = __builtin_amdgcn_mfma_f32_16x16x32_bf16(
                        af[i][ks], bw[ks], acc[i], 0, 0, 0);
            }
#pragma unroll
        for (int i = 0; i < 3; ++i) {
            int mt = wave + 4 * i;
            if (mt < 9) {
#pragma unroll
                for (int r = 0; r < 4; ++r) {
                    float v = acc[i][r] + bias;
                    int tok = mt * 16 + quad * 4 + r;
                    if (nt < 2)      Qs[tok * 36 + nt * 16 + l15] = f2bf(v);
                    else if (nt < 4) Ks[tok * 36 + (nt - 2) * 16 + l15] = f2bf(v);
                    else             VTs[((nt - 4) * 16 + l15) * 168 + tok] = f2bf(v);
                }
            }
        }
    }
    __syncthreads();

    // ---- S = Q K^T + bias ----
    bf16x8 qa[3];
#pragma unroll
    for (int i = 0; i < 3; ++i) {
        int mt = wave + 4 * i;
        if (mt < 9) qa[i] = ld8h(Qs + (mt * 16 + l15) * 36 + quad * 8);
    }
    f32x4 sa[3][9];
    for (int nt = 0; nt < 9; ++nt) {
        bf16x8 kb = ld8h(Ks + (nt * 16 + l15) * 36 + quad * 8);
#pragma unroll
        for (int i = 0; i < 3; ++i) {
            int mt = wave + 4 * i;
            sa[i][nt] = (f32x4){0.f, 0.f, 0.f, 0.f};
            if (mt < 9)
                sa[i][nt] = __builtin_amdgcn_mfma_f32_16x16x32_bf16(
                    qa[i], kb, sa[i][nt], 0, 0, 0);
        }
    }
    const bf16* bt = biasT + (size_t)(wb * 6 + head) * 20736;
#pragma unroll
    for (int i = 0; i < 3; ++i) {
        int mt = wave + 4 * i;
        if (mt < 9) {
#pragma unroll
            for (int nt = 0; nt < 9; ++nt)
#pragma unroll
                for (int r = 0; r < 4; ++r) {
                    int row = mt * 16 + quad * 4 + r;
                    sa[i][nt][r] += bf2f(bt[row * 144 + nt * 16 + l15]);
                }
        }
    }

    // ---- softmax (in-register, rows in quad) -> P (bf16 LDS, pad zeroed) ----
#pragma unroll
    for (int i = 0; i < 3; ++i) {
        int mt = wave + 4 * i;
        if (mt < 9) {
#pragma unroll
            for (int r = 0; r < 4; ++r) {
                float mx = -1e30f;
#pragma unroll
                for (int nt = 0; nt < 9; ++nt) mx = fmaxf(mx, sa[i][nt][r]);
#pragma unroll
                for (int msk = 1; msk < 16; msk <<= 1)
                    mx = fmaxf(mx, __shfl_xor(mx, msk, 64));
                float s = 0.f;
#pragma unroll
                for (int nt = 0; nt < 9; ++nt) {
                    float e = __expf(sa[i][nt][r] - mx);
                    sa[i][nt][r] = e;
                    s += e;
                }
#pragma unroll
                for (int msk = 1; msk < 16; msk <<= 1)
                    s += __shfl_xor(s, msk, 64);
                float inv = 1.f / s;
                int row = mt * 16 + quad * 4 + r;
#pragma unroll
                for (int nt = 0; nt < 9; ++nt)
                    Ps[row * 168 + nt * 16 + l15] = f2bf(sa[i][nt][r] * inv);
                Ps[row * 168 + 144 + l15] = f2bf(0.f);
            }
        }
    }

    // ---- O = P V  (K padded to 160 with zeros) ----
    f32x4 oa[3][2];
#pragma unroll
    for (int i = 0; i < 3; ++i)
#pragma unroll
        for (int n2 = 0; n2 < 2; ++n2) oa[i][n2] = (f32x4){0.f, 0.f, 0.f, 0.f};
#pragma unroll
    for (int ks = 0; ks < 5; ++ks) {
        bf16x8 vb[2];
#pragma unroll
        for (int n2 = 0; n2 < 2; ++n2)
            vb[n2] = *(const bf16x8*)(VTs + (n2 * 16 + l15) * 168 + ks * 32 + quad * 8);
#pragma unroll
        for (int i = 0; i < 3; ++i) {
            int mt = wave + 4 * i;
            if (mt < 9) {
                bf16x8 pa = *(const bf16x8*)(Ps + (mt * 16 + l15) * 168 + ks * 32 + quad * 8);
#pragma unroll
                for (int n2 = 0; n2 < 2; ++n2)
                    oa[i][n2] = __builtin_amdgcn_mfma_f32_16x16x32_bf16(
                        pa, vb[n2], oa[i][n2], 0, 0, 0);
            }
        }
    }

    // ---- store attn_out (same layout as before) ----
#pragma unroll
    for (int i = 0; i < 3; ++i) {
        int mt = wave + 4 * i;
        if (mt < 9) {
#pragma unroll
            for (int n2 = 0; n2 < 2; ++n2)
#pragma unroll
                for (int r = 0; r < 4; ++r) {
                    int tok = mt * 16 + quad * 4 + r;
                    attn_out[(size_t)(wi * 144 + tok) * 192 + (head << 5) + n2 * 16 + l15]
                        = f2bf(oa[i][n2][r]);
                }
        }
    }
}

// ---------------------------------------------------------------------------
// Kernel 2 (MFMA): proj + window-reverse/crop + LN1 + residual -> x1
// 128 tokens/block (8 M-tiles), 4 waves x 48 cols (3 N-tiles), K=192 (6 steps).
// proj_w converted fp32->bf16 on the fly (each fragment feeds 8 MFMAs; no
// prepped bf16 copy exists because the low workspace region is live with attn
// rows while this kernel runs).
// ---------------------------------------------------------------------------
__global__ __launch_bounds__(256, 2) void proj_mfma_kernel(
    const bf16* __restrict__ attn, const float* __restrict__ proj_w,
    const float* __restrict__ proj_b, const float* __restrict__ xin,
    const float* __restrict__ n1w, const float* __restrict__ n1b,
    bf16* __restrict__ x1out)
{
    // LDS: Xs [128][200] bf16 @0 (51200) | wsum [128][4] @51200 (2048)
    //      wsq [128][4] @53248 (2048) | mean [128] @55296 | rstd [128] @55808
    __shared__ alignas(16) char sm[56320];
    bf16*  Xs     = (bf16*)sm;
    float* wsum   = (float*)(sm + 51200);
    float* wsq    = (float*)(sm + 53248);
    float* mean_s = (float*)(sm + 55296);
    float* rstd_s = (float*)(sm + 55808);

    const int tid  = threadIdx.x;
    const int wave = tid >> 6;
    const int lane = tid & 63;
    const int quad = lane >> 4;
    const int l15  = lane & 15;
    const long tok0 = (long)blockIdx.x * 128;
    const int colw = wave * 48;

    // ---- gather attn rows (window reverse + crop) into Xs ----
    for (int i = tid; i < 128 * 24; i += 256) {
        int r = i / 24, c4 = i - r * 24;
        long l = tok0 + r;
        uint4 v = make_uint4(0u, 0u, 0u, 0u);
        if (l < 131040) {
            int li  = (int)l;
            int z   = li / 16380, rem = li - z * 16380;
            int lat = rem / 180, lon = rem - lat * 180;
            int latp = lat + 2;
            int zw = z >> 1, tz = z & 1;
            int hw = latp / 6, th = latp - hw * 6;
            int wwn = lon / 12, tw = lon - wwn * 12;
            int wi = (zw * 16 + hw) * 15 + wwn;
            int t  = (tz * 6 + th) * 12 + tw;
            v = *(const uint4*)(attn + (size_t)(wi * 144 + t) * 192 + c4 * 8);
        }
        *(uint4*)(Xs + r * 200 + c4 * 8) = v;
    }
    __syncthreads();

    // ---- GEMM: o[nt][mt] = Xs @ proj_w.T (wave's 48-col slice) ----
    f32x4 o[3][8];
#pragma unroll
    for (int nt = 0; nt < 3; ++nt)
#pragma unroll
        for (int mt = 0; mt < 8; ++mt)
            o[nt][mt] = (f32x4){0.f, 0.f, 0.f, 0.f};

#pragma unroll
    for (int ks = 0; ks < 6; ++ks) {
        bf16x8 wfr[3];
#pragma unroll
        for (int nt = 0; nt < 3; ++nt) {
            const float* wp = proj_w + (size_t)(colw + nt * 16 + l15) * 192
                            + ks * 32 + quad * 8;
            float4 lo = *(const float4*)wp;
            float4 hi = *(const float4*)(wp + 4);
            wfr[nt] = pack8(lo, hi);
        }
#pragma unroll
        for (int mt = 0; mt < 8; ++mt) {
            bf16x8 a = *(const bf16x8*)(Xs + (mt * 16 + l15) * 200 + ks * 32 + quad * 8);
#pragma unroll
            for (int nt = 0; nt < 3; ++nt)
                o[nt][mt] = __builtin_amdgcn_mfma_f32_16x16x32_bf16(
                    a, wfr[nt], o[nt][mt], 0, 0, 0);
        }
    }

    // ---- + proj bias ----
    float pbv[3], gw[3], gb[3];
#pragma unroll
    for (int nt = 0; nt < 3; ++nt) {
        int c = colw + nt * 16 + l15;
        pbv[nt] = proj_b[c];
        gw[nt]  = n1w[c];
        gb[nt]  = n1b[c];
    }
#pragma unroll
    for (int nt = 0; nt < 3; ++nt)
#pragma unroll
        for (int mt = 0; mt < 8; ++mt)
#pragma unroll
            for (int r = 0; r < 4; ++r)
                o[nt][mt][r] += pbv[nt];

    // ---- LN1 row stats (cross-wave via LDS) ----
#pragma unroll
    for (int mt = 0; mt < 8; ++mt) {
#pragma unroll
        for (int r = 0; r < 4; ++r) {
            float p = o[0][mt][r] + o[1][mt][r] + o[2][mt][r];
            float q = o[0][mt][r] * o[0][mt][r] + o[1][mt][r] * o[1][mt][r]
                    + o[2][mt][r] * o[2][mt][r];
#pragma unroll
            for (int m_ = 1; m_ < 16; m_ <<= 1) {
                p += __shfl_xor(p, m_, 64);
                q += __shfl_xor(q, m_, 64);
            }
            if (l15 == 0) {
                int row = mt * 16 + quad * 4 + r;
                wsum[row * 4 + wave] = p;
                wsq [row * 4 + wave] = q;
            }
        }
    }
    __syncthreads();
    if (tid < 128) {
        float s  = wsum[tid * 4] + wsum[tid * 4 + 1] + wsum[tid * 4 + 2] + wsum[tid * 4 + 3];
        float ss = wsq [tid * 4] + wsq [tid * 4 + 1] + wsq [tid * 4 + 2] + wsq [tid * 4 + 3];
        float m = s * (1.f / 192.f);
        float var = ss * (1.f / 192.f) - m * m;
        mean_s[tid] = m;
        rstd_s[tid] = rsqrtf(fmaxf(var, 0.f) + 1e-5f);
    }
    __syncthreads();

    // ---- x1 = xin + LN1(proj_out) ----
#pragma unroll
    for (int mt = 0; mt < 8; ++mt) {
#pragma unroll
        for (int r = 0; r < 4; ++r) {
            int row = mt * 16 + quad * 4 + r;
            long tok = tok0 + row;
            if (tok < 131040) {
                float m = mean_s[row], rsd = rstd_s[row];
#pragma unroll
                for (int nt = 0; nt < 3; ++nt) {
                    int c = colw + nt * 16 + l15;
                    float val = (o[nt][mt][r] - m) * rsd * gw[nt] + gb[nt]
                              + xin[(size_t)tok * 192 + c];
                    x1out[(size_t)tok * 192 + c] = f2bf(val);
                }
            }
        }
    }
}

// ---------------------------------------------------------------------------
// Prep C: convert w1/w2 fp32 -> bf16 (unchanged)
// ---------------------------------------------------------------------------
__global__ __launch_bounds__(256) void prep_weights(
    const float* __restrict__ w1, const float* __restrict__ w2,
    unsigned int* __restrict__ w1b, unsigned int* __restrict__ w2b)
{
    int i = blockIdx.x * 256 + threadIdx.x;
    if (i < 73728) {
        w1b[i] = pack2(w1[2 * i], w1[2 * i + 1]);
    } else {
        int j = i - 73728;
        w2b[j] = pack2(w2[2 * j], w2[2 * j + 1]);
    }
}

// ---------------------------------------------------------------------------
// Kernel 3 (MFMA): fused MLP + LN2 + residual (unchanged)
// ---------------------------------------------------------------------------
__global__ __launch_bounds__(256, 2) void mlp_mfma_kernel(
    const bf16* __restrict__ x1, const bf16* __restrict__ w1b,
    const float* __restrict__ b1, const bf16* __restrict__ w2b,
    const float* __restrict__ b2, const float* __restrict__ n2w,
    const float* __restrict__ n2b, float* __restrict__ out)
{
    __shared__ alignas(16) char sm[53760];
    bf16*  Xs     = (bf16*)sm;
    bf16*  Hs     = (bf16*)(sm + 25600);
    float* wsum   = (float*)(sm + 51200);
    float* wsq    = (float*)(sm + 52224);
    float* mean_s = (float*)(sm + 53248);
    float* rstd_s = (float*)(sm + 53504);

    const int tid  = threadIdx.x;
    const int wave = tid >> 6;
    const int lane = tid & 63;
    const int quad = lane >> 4;
    const int l15  = lane & 15;
    const long tok0 = (long)blockIdx.x * 64;
    const int colw = wave * 48;

    for (int i = tid; i < 64 * 24; i += 256) {
        int r = i / 24, c8 = i - r * 24;
        uint4 v = make_uint4(0u, 0u, 0u, 0u);
        if (tok0 + r < 131040)
            v = *(const uint4*)(x1 + (tok0 + r) * 192 + (size_t)c8 * 8);
        *(uint4*)(Xs + r * 200 + c8 * 8) = v;
    }
    __syncthreads();

    bf16x8 af[4][6];
#pragma unroll
    for (int mt = 0; mt < 4; ++mt)
#pragma unroll
        for (int ks = 0; ks < 6; ++ks)
            af[mt][ks] = *(const bf16x8*)(Xs + (mt * 16 + l15) * 200 + ks * 32 + quad * 8);

    f32x4 o[3][4];
#pragma unroll
    for (int nt = 0; nt < 3; ++nt)
#pragma unroll
        for (int mt = 0; mt < 4; ++mt)
            o[nt][mt] = (f32x4){0.f, 0.f, 0.f, 0.f};

    for (int nc = 0; nc < 4; ++nc) {
        f32x4 g[3][4];
#pragma unroll
        for (int nt = 0; nt < 3; ++nt)
#pragma unroll
            for (int mt = 0; mt < 4; ++mt)
                g[nt][mt] = (f32x4){0.f, 0.f, 0.f, 0.f};
        const int h0 = nc * 192 + colw;
#pragma unroll
        for (int ks = 0; ks < 6; ++ks) {
            bf16x8 bfr[3];
#pragma unroll
            for (int nt = 0; nt < 3; ++nt)
                bfr[nt] = *(const bf16x8*)(w1b + (size_t)(h0 + nt * 16 + l15) * 192 + ks * 32 + quad * 8);
#pragma unroll
            for (int nt = 0; nt < 3; ++nt)
#pragma unroll
                for (int mt = 0; mt < 4; ++mt)
                    g[nt][mt] = __builtin_amdgcn_mfma_f32_16x16x32_bf16(
                        af[mt][ks], bfr[nt], g[nt][mt], 0, 0, 0);
        }
        __syncthreads();

#pragma unroll
        for (int nt = 0; nt < 3; ++nt) {
            float bb = b1[h0 + nt * 16 + l15];
            int hcol = colw + nt * 16 + l15;
#pragma unroll
            for (int mt = 0; mt < 4; ++mt) {
#pragma unroll
                for (int r = 0; r < 4; ++r) {
                    float v = g[nt][mt][r] + bb;
                    float u = v * (0.7978845608028654f + 0.035677408136300125f * v * v);
                    float e = __expf(2.f * u);
                    float t = 1.f - 2.f / (e + 1.f);
                    float gl = 0.5f * v * (1.f + t);
                    Hs[(mt * 16 + quad * 4 + r) * 200 + hcol] = f2bf(gl);
                }
            }
        }
        __syncthreads();

#pragma unroll
        for (int ks = 0; ks < 6; ++ks) {
            bf16x8 hf[4];
#pragma unroll
            for (int mt = 0; mt < 4; ++mt)
                hf[mt] = *(const bf16x8*)(Hs + (mt * 16 + l15) * 200 + ks * 32 + quad * 8);
            bf16x8 wf[3];
#pragma unroll
            for (int nt = 0; nt < 3; ++nt)
                wf[nt] = *(const bf16x8*)(w2b + (size_t)(colw + nt * 16 + l15) * 768 + nc * 192 + ks * 32 + quad * 8);
#pragma unroll
            for (int nt = 0; nt < 3; ++nt)
#pragma unroll
                for (int mt = 0; mt < 4; ++mt)
                    o[nt][mt] = __builtin_amdgcn_mfma_f32_16x16x32_bf16(
                        hf[mt], wf[nt], o[nt][mt], 0, 0, 0);
        }
    }

    float b2v[3], gw[3], gb[3];
#pragma unroll
    for (int nt = 0; nt < 3; ++nt) {
        int c = colw + nt * 16 + l15;
        b2v[nt] = b2[c];
        gw[nt] = n2w[c];
        gb[nt] = n2b[c];
    }
#pragma unroll
    for (int nt = 0; nt < 3; ++nt)
#pragma unroll
        for (int mt = 0; mt < 4; ++mt)
#pragma unroll
            for (int r = 0; r < 4; ++r)
                o[nt][mt][r] += b2v[nt];

#pragma unroll
    for (int mt = 0; mt < 4; ++mt) {
#pragma unroll
        for (int r = 0; r < 4; ++r) {
            float p = o[0][mt][r] + o[1][mt][r] + o[2][mt][r];
            float q = o[0][mt][r] * o[0][mt][r] + o[1][mt][r] * o[1][mt][r]
                    + o[2][mt][r] * o[2][mt][r];
#pragma unroll
            for (int m_ = 1; m_ < 16; m_ <<= 1) {
                p += __shfl_xor(p, m_, 64);
                q += __shfl_xor(q, m_, 64);
            }
            if (l15 == 0) {
                int row = mt * 16 + quad * 4 + r;
                wsum[row * 4 + wave] = p;
                wsq [row * 4 + wave] = q;
            }
        }
    }
    __syncthreads();
    if (tid < 64) {
        float s  = wsum[tid * 4] + wsum[tid * 4 + 1] + wsum[tid * 4 + 2] + wsum[tid * 4 + 3];
        float ss = wsq [tid * 4] + wsq [tid * 4 + 1] + wsq [tid * 4 + 2] + wsq [tid * 4 + 3];
        float m = s * (1.f / 192.f);
        float var = ss * (1.f / 192.f) - m * m;
        mean_s[tid] = m;
        rstd_s[tid] = rsqrtf(fmaxf(var, 0.f) + 1e-5f);
    }
    __syncthreads();

#pragma unroll
    for (int mt = 0; mt < 4; ++mt) {
#pragma unroll
        for (int r = 0; r < 4; ++r) {
            int row = mt * 16 + quad * 4 + r;
            long tok = tok0 + row;
            if (tok < 131040) {
                float m = mean_s[row], rsd = rstd_s[row];
#pragma unroll
                for (int nt = 0; nt < 3; ++nt) {
                    int c = colw + nt * 16 + l15;
                    float val = (o[nt][mt][r] - m) * rsd * gw[nt] + gb[nt]
                              + bf2f(Xs[row * 200 + c]);
                    out[tok * 192 + c] = val;
                }
            }
        }
    }
}

// ---------------------------------------------------------------------------
extern "C" void kernel_launch(void* const* d_in, const int* in_sizes, int n_in,
                              void* d_out, int out_size, void* d_ws, size_t ws_size,
                              hipStream_t stream) {
    (void)in_sizes; (void)n_in; (void)out_size; (void)ws_size;
    const float* x          = (const float*)d_in[0];
    const float* qkv_w      = (const float*)d_in[1];
    const float* qkv_b      = (const float*)d_in[2];
    const float* proj_w     = (const float*)d_in[3];
    const float* proj_b     = (const float*)d_in[4];
    const float* bias_table = (const float*)d_in[5];
    const float* n1w        = (const float*)d_in[6];
    const float* n1b        = (const float*)d_in[7];
    const float* n2w        = (const float*)d_in[8];
    const float* n2b        = (const float*)d_in[9];
    const float* w1         = (const float*)d_in[10];
    const float* b1         = (const float*)d_in[11];
    const float* w2         = (const float*)d_in[12];
    const float* b2         = (const float*)d_in[13];
    float* out = (float*)d_out;

    // ws layout:
    //  [0, 53084160)            attn rows bf16 (dead after proj; start reused for w1b/w2b)
    //  [53084160, +50319360)    x1 bf16 (written by proj). BEFORE proj runs, this
    //                           region hosts attn prep data (read only by attn):
    //    qkv_wb @53084160 (221184 B) | qkv_bb @53305344 (2304 B) | biasT @53307648 (15925248 B)
    bf16*  attn_ws = (bf16*)d_ws;
    bf16*  x1_ws   = (bf16*)((char*)d_ws + 53084160);
    bf16*  w1b     = (bf16*)d_ws;
    bf16*  w2b     = (bf16*)((char*)d_ws + 294912);
    bf16*  qkv_wb  = (bf16*)((char*)d_ws + 53084160);
    float* qkv_bb  = (float*)((char*)d_ws + 53305344);
    bf16*  biasT   = (bf16*)((char*)d_ws + 53307648);

    prep_attn_w<<<432, 256, 0, stream>>>(qkv_w, qkv_b, qkv_wb, qkv_bb);
    prep_bias<<<31104, 256, 0, stream>>>(bias_table, biasT);
    attn_mfma_kernel<<<dim3(960, 6), 256, 0, stream>>>(x, qkv_wb, qkv_bb, biasT, attn_ws);
    proj_mfma_kernel<<<1024, 256, 0, stream>>>(attn_ws, proj_w, proj_b, x, n1w, n1b, x1_ws);
    prep_weights<<<576, 256, 0, stream>>>(w1, w2, (unsigned int*)w1b, (unsigned int*)w2b);
    mlp_mfma_kernel<<<2048, 256, 0, stream>>>(x1_ws, w1b, b1, w2b, b2, n2w, n2b, out);
}